// Round 1
// baseline (207.950 us; speedup 1.0000x reference)
//
#include <hip/hip_runtime.h>

#define BB 4
#define H 320
#define W 768
#define P (H*W)           // 245760
#define NPIX (BB*P)       // 983040

#define TX 32
#define TY 8
#define TW (TX+6)  // 38
#define TH (TY+6)  // 14

// ---------------- gray kernel (+ zero out) ----------------
__global__ void gray_kernel(const float* __restrict__ former,
                            const float* __restrict__ latter,
                            float* __restrict__ gf, float* __restrict__ gl,
                            float* __restrict__ out) {
    int idx = blockIdx.x * blockDim.x + threadIdx.x;
    if (idx == 0) { out[0] = 0.f; out[1] = 0.f; }
    if (idx >= NPIX) return;
    int b = idx / P;
    int r = idx - b * P;
    const float* f = former + (size_t)b * 3 * P + r;
    const float* l = latter + (size_t)b * 3 * P + r;
    gf[idx] = (0.299f * f[0] + 0.587f * f[P] + 0.114f * f[2 * P]) * 255.f;
    gl[idx] = (0.299f * l[0] + 0.587f * l[P] + 0.114f * l[2 * P]) * 255.f;
}

// ---------------- bilinear warp ----------------
__device__ __forceinline__ float bilinear(const float* __restrict__ img, float fx, float fy) {
    float x0 = floorf(fx), y0 = floorf(fy);
    float wx = fx - x0, wy = fy - y0;
    float x0c = fminf(fmaxf(x0,       0.f), (float)(W - 1));
    float x1c = fminf(fmaxf(x0 + 1.f, 0.f), (float)(W - 1));
    float y0c = fminf(fmaxf(y0,       0.f), (float)(H - 1));
    float y1c = fminf(fmaxf(y0 + 1.f, 0.f), (float)(H - 1));
    int x0i = (int)x0c, x1i = (int)x1c, y0i = (int)y0c, y1i = (int)y1c;
    float Ia = img[y0i * W + x0i], Ib = img[y0i * W + x1i];
    float Ic = img[y1i * W + x0i], Id = img[y1i * W + x1i];
    float omx = 1.f - wx, omy = 1.f - wy;
    return Ia * omx * omy + Ib * wx * omy + Ic * omx * wy + Id * wx * wy;
}

__global__ void warp_kernel(const float* __restrict__ gl, const float* __restrict__ gf,
                            const float* __restrict__ flow1, const float* __restrict__ flow2,
                            float* __restrict__ gw1, float* __restrict__ gw2) {
    int idx = blockIdx.x * blockDim.x + threadIdx.x;
    if (idx >= NPIX) return;
    int b = idx / P;
    int r = idx - b * P;
    int y = r / W;
    int x = r - y * W;
    {
        float u = flow1[(size_t)b * 2 * P + r];
        float v = flow1[(size_t)b * 2 * P + P + r];
        gw1[idx] = bilinear(gl + (size_t)b * P, (float)x + u, (float)y + v);
    }
    {
        float u = flow2[(size_t)b * 2 * P + r];
        float v = flow2[(size_t)b * 2 * P + P + r];
        gw2[idx] = bilinear(gf + (size_t)b * P, (float)x + u, (float)y + v);
    }
}

// ---------------- census + distance + charbonnier + reduce ----------------
__global__ __launch_bounds__(256)
void census_kernel(const float* __restrict__ gf, const float* __restrict__ gw1,
                   const float* __restrict__ gl, const float* __restrict__ gw2,
                   const float* __restrict__ fw_mask, const float* __restrict__ bw_mask,
                   float* __restrict__ out) {
    __shared__ float sA[TH * TW], sB[TH * TW], sC[TH * TW], sD[TH * TW];
    const int b   = blockIdx.z;
    const int tx0 = blockIdx.x * TX;
    const int ty0 = blockIdx.y * TY;
    const int tid = threadIdx.x;

    const float* pA = gf  + (size_t)b * P;
    const float* pB = gw1 + (size_t)b * P;
    const float* pC = gl  + (size_t)b * P;
    const float* pD = gw2 + (size_t)b * P;

    for (int i = tid; i < TH * TW; i += 256) {
        int ly = i / TW, lx = i - ly * TW;
        int gx = tx0 - 3 + lx, gy = ty0 - 3 + ly;
        bool ok = (gx >= 0) & (gx < W) & (gy >= 0) & (gy < H);
        int o = gy * W + gx;
        sA[i] = ok ? pA[o] : 0.f;
        sB[i] = ok ? pB[o] : 0.f;
        sC[i] = ok ? pC[o] : 0.f;
        sD[i] = ok ? pD[o] : 0.f;
    }
    __syncthreads();

    const int lx = tid & 31, ly = tid >> 5;
    const int x = tx0 + lx, y = ty0 + ly;
    float sum1 = 0.f, sum2 = 0.f;

    if (x >= 3 && x < W - 3 && y >= 3 && y < H - 3) {
        const int c = (ly + 3) * TW + (lx + 3);
        const float c1 = sA[c], c2 = sB[c], c3 = sC[c], c4 = sD[c];
        float dist1 = 0.f, dist2 = 0.f;
#pragma unroll
        for (int dy = 0; dy < 7; ++dy) {
#pragma unroll
            for (int dx = 0; dx < 7; ++dx) {
                int o = (ly + dy) * TW + (lx + dx);
                float a = sA[o] - c1;
                float bb = sB[o] - c2;
                a  *= __builtin_amdgcn_rsqf(0.81f + a * a);
                bb *= __builtin_amdgcn_rsqf(0.81f + bb * bb);
                float d = a - bb; d *= d;
                dist1 += d * __builtin_amdgcn_rcpf(0.1f + d);

                float e = sC[o] - c3;
                float f = sD[o] - c4;
                e *= __builtin_amdgcn_rsqf(0.81f + e * e);
                f *= __builtin_amdgcn_rsqf(0.81f + f * f);
                float d2 = e - f; d2 *= d2;
                dist2 += d2 * __builtin_amdgcn_rcpf(0.1f + d2);
            }
        }
        const float m1 = fw_mask[(size_t)b * P + y * W + x];
        const float m2 = bw_mask[(size_t)b * P + y * W + x];
        sum1 = exp2f(0.45f * log2f(dist1 * dist1 + 1e-6f)) * m1;
        sum2 = exp2f(0.45f * log2f(dist2 * dist2 + 1e-6f)) * m2;
    }

    // wave (64) shuffle reduce
#pragma unroll
    for (int off = 32; off; off >>= 1) {
        sum1 += __shfl_down(sum1, off, 64);
        sum2 += __shfl_down(sum2, off, 64);
    }
    __shared__ float red[8];
    const int wave = tid >> 6, lane = tid & 63;
    if (lane == 0) { red[wave] = sum1; red[4 + wave] = sum2; }
    __syncthreads();
    if (tid == 0) {
        float s1 = red[0] + red[1] + red[2] + red[3];
        float s2 = red[4] + red[5] + red[6] + red[7];
        atomicAdd(&out[0], s1 * (1.0f / NPIX));
        atomicAdd(&out[1], s2 * (1.0f / NPIX));
    }
}

extern "C" void kernel_launch(void* const* d_in, const int* in_sizes, int n_in,
                              void* d_out, int out_size, void* d_ws, size_t ws_size,
                              hipStream_t stream) {
    (void)in_sizes; (void)n_in; (void)out_size; (void)ws_size;
    const float* former  = (const float*)d_in[0];
    const float* latter  = (const float*)d_in[1];
    const float* flow1   = (const float*)d_in[2];
    const float* flow2   = (const float*)d_in[3];
    const float* fw_mask = (const float*)d_in[4];
    const float* bw_mask = (const float*)d_in[5];
    float* out = (float*)d_out;
    float* ws  = (float*)d_ws;
    float* gf  = ws;
    float* gl  = ws + NPIX;
    float* gw1 = ws + 2 * (size_t)NPIX;
    float* gw2 = ws + 3 * (size_t)NPIX;

    gray_kernel<<<(NPIX + 255) / 256, 256, 0, stream>>>(former, latter, gf, gl, out);
    warp_kernel<<<(NPIX + 255) / 256, 256, 0, stream>>>(gl, gf, flow1, flow2, gw1, gw2);
    census_kernel<<<dim3(W / TX, H / TY, BB), 256, 0, stream>>>(gf, gw1, gl, gw2,
                                                                fw_mask, bw_mask, out);
}

// Round 2
// 139.863 us; speedup vs baseline: 1.4868x; 1.4868x over previous
//
#include <hip/hip_runtime.h>

#define BB 4
#define H 320
#define W 768
#define P (H*W)           // 245760
#define NPIX (BB*P)       // 983040

#define TX 32
#define TY 8
#define TW (TX+6)  // 38
#define TH (TY+6)  // 14
#define HALO (TW*TH)      // 532
#define NBX (W/TX)        // 24
#define NBY (H/TY)        // 40
#define NBLK (NBX*NBY*BB) // 3840

// ---------------- gray kernel ----------------
__global__ void gray_kernel(const float* __restrict__ former,
                            const float* __restrict__ latter,
                            float* __restrict__ gf, float* __restrict__ gl) {
    int idx = blockIdx.x * blockDim.x + threadIdx.x;
    if (idx >= NPIX) return;
    int b = idx / P;
    int r = idx - b * P;
    const float* f = former + (size_t)b * 3 * P + r;
    const float* l = latter + (size_t)b * 3 * P + r;
    gf[idx] = (0.299f * f[0] + 0.587f * f[P] + 0.114f * f[2 * P]) * 255.f;
    gl[idx] = (0.299f * l[0] + 0.587f * l[P] + 0.114f * l[2 * P]) * 255.f;
}

__device__ __forceinline__ float bilinear(const float* __restrict__ img, float fx, float fy) {
    float x0 = floorf(fx), y0 = floorf(fy);
    float wx = fx - x0, wy = fy - y0;
    float x0c = fminf(fmaxf(x0,       0.f), (float)(W - 1));
    float x1c = fminf(fmaxf(x0 + 1.f, 0.f), (float)(W - 1));
    float y0c = fminf(fmaxf(y0,       0.f), (float)(H - 1));
    float y1c = fminf(fmaxf(y0 + 1.f, 0.f), (float)(H - 1));
    int x0i = (int)x0c, x1i = (int)x1c, y0i = (int)y0c, y1i = (int)y1c;
    float Ia = img[y0i * W + x0i], Ib = img[y0i * W + x1i];
    float Ic = img[y1i * W + x0i], Id = img[y1i * W + x1i];
    float omx = 1.f - wx, omy = 1.f - wy;
    return Ia * omx * omy + Ib * wx * omy + Ic * omx * wy + Id * wx * wy;
}

// ---------------- fused warp + census + distance + charbonnier ----------------
__global__ __launch_bounds__(256)
void fused_kernel(const float* __restrict__ gf, const float* __restrict__ gl,
                  const float* __restrict__ flow1, const float* __restrict__ flow2,
                  const float* __restrict__ fw_mask, const float* __restrict__ bw_mask,
                  float* __restrict__ partials) {
    __shared__ float sA[HALO], sB[HALO], sC[HALO], sD[HALO];
    const int b   = blockIdx.z;
    const int tx0 = blockIdx.x * TX;
    const int ty0 = blockIdx.y * TY;
    const int tid = threadIdx.x;

    const float* pGF = gf + (size_t)b * P;
    const float* pGL = gl + (size_t)b * P;
    const float* pF1 = flow1 + (size_t)b * 2 * P;
    const float* pF2 = flow2 + (size_t)b * 2 * P;

    // Stage 1: load gray tiles and compute warped tiles into LDS.
    // Interior outputs only use in-bounds halo pixels; clamping is fine for
    // out-of-bounds halo (those feed only masked border outputs).
    for (int i = tid; i < HALO; i += 256) {
        int ly = i / TW, lx = i - ly * TW;
        int gx = min(max(tx0 - 3 + lx, 0), W - 1);
        int gy = min(max(ty0 - 3 + ly, 0), H - 1);
        int o = gy * W + gx;
        sA[i] = pGF[o];
        sC[i] = pGL[o];
        float u1 = pF1[o], v1 = pF1[P + o];
        float u2 = pF2[o], v2 = pF2[P + o];
        sB[i] = bilinear(pGL, (float)gx + u1, (float)gy + v1);
        sD[i] = bilinear(pGF, (float)gx + u2, (float)gy + v2);
    }
    __syncthreads();

    const int lx = tid & 31, ly = tid >> 5;
    const int x = tx0 + lx, y = ty0 + ly;
    float sum1 = 0.f, sum2 = 0.f;

    if (x >= 3 && x < W - 3 && y >= 3 && y < H - 3) {
        const int c = (ly + 3) * TW + (lx + 3);
        const float c1 = sA[c], c2 = sB[c], c3 = sC[c], c4 = sD[c];
        float dist1 = 0.f, dist2 = 0.f;
#pragma unroll
        for (int dy = 0; dy < 7; ++dy) {
            const int ro = (ly + dy) * TW + lx;
            float a[7], bv[7], cv[7], dv[7];
#pragma unroll
            for (int dx = 0; dx < 7; ++dx) { a[dx] = sA[ro + dx]; bv[dx] = sB[ro + dx]; }
#pragma unroll
            for (int dx = 0; dx < 7; ++dx) { cv[dx] = sC[ro + dx]; dv[dx] = sD[ro + dx]; }
#pragma unroll
            for (int dx = 0; dx < 7; ++dx) {
                float t1 = a[dx] - c1;
                float t2 = bv[dx] - c2;
                t1 *= __builtin_amdgcn_rsqf(0.81f + t1 * t1);
                t2 *= __builtin_amdgcn_rsqf(0.81f + t2 * t2);
                float d = t1 - t2; d *= d;
                dist1 += d * __builtin_amdgcn_rcpf(0.1f + d);
            }
#pragma unroll
            for (int dx = 0; dx < 7; ++dx) {
                float t3 = cv[dx] - c3;
                float t4 = dv[dx] - c4;
                t3 *= __builtin_amdgcn_rsqf(0.81f + t3 * t3);
                t4 *= __builtin_amdgcn_rsqf(0.81f + t4 * t4);
                float d = t3 - t4; d *= d;
                dist2 += d * __builtin_amdgcn_rcpf(0.1f + d);
            }
        }
        const float m1 = fw_mask[(size_t)b * P + y * W + x];
        const float m2 = bw_mask[(size_t)b * P + y * W + x];
        sum1 = exp2f(0.45f * log2f(dist1 * dist1 + 1e-6f)) * m1;
        sum2 = exp2f(0.45f * log2f(dist2 * dist2 + 1e-6f)) * m2;
    }

#pragma unroll
    for (int off = 32; off; off >>= 1) {
        sum1 += __shfl_down(sum1, off, 64);
        sum2 += __shfl_down(sum2, off, 64);
    }
    __shared__ float red[8];
    const int wave = tid >> 6, lane = tid & 63;
    if (lane == 0) { red[wave] = sum1; red[4 + wave] = sum2; }
    __syncthreads();
    if (tid == 0) {
        const int blk = (blockIdx.z * NBY + blockIdx.y) * NBX + blockIdx.x;
        partials[2 * blk]     = red[0] + red[1] + red[2] + red[3];
        partials[2 * blk + 1] = red[4] + red[5] + red[6] + red[7];
    }
}

// ---------------- final reduce ----------------
__global__ __launch_bounds__(256)
void reduce_kernel(const float* __restrict__ partials, float* __restrict__ out) {
    const int tid = threadIdx.x;
    float s1 = 0.f, s2 = 0.f;
    for (int i = tid; i < NBLK; i += 256) {
        s1 += partials[2 * i];
        s2 += partials[2 * i + 1];
    }
#pragma unroll
    for (int off = 32; off; off >>= 1) {
        s1 += __shfl_down(s1, off, 64);
        s2 += __shfl_down(s2, off, 64);
    }
    __shared__ float red[8];
    const int wave = tid >> 6, lane = tid & 63;
    if (lane == 0) { red[wave] = s1; red[4 + wave] = s2; }
    __syncthreads();
    if (tid == 0) {
        out[0] = (red[0] + red[1] + red[2] + red[3]) * (1.0f / NPIX);
        out[1] = (red[4] + red[5] + red[6] + red[7]) * (1.0f / NPIX);
    }
}

extern "C" void kernel_launch(void* const* d_in, const int* in_sizes, int n_in,
                              void* d_out, int out_size, void* d_ws, size_t ws_size,
                              hipStream_t stream) {
    (void)in_sizes; (void)n_in; (void)out_size; (void)ws_size;
    const float* former  = (const float*)d_in[0];
    const float* latter  = (const float*)d_in[1];
    const float* flow1   = (const float*)d_in[2];
    const float* flow2   = (const float*)d_in[3];
    const float* fw_mask = (const float*)d_in[4];
    const float* bw_mask = (const float*)d_in[5];
    float* out = (float*)d_out;
    float* ws  = (float*)d_ws;
    float* gf       = ws;
    float* gl       = ws + NPIX;
    float* partials = ws + 2 * (size_t)NPIX;

    gray_kernel<<<(NPIX + 255) / 256, 256, 0, stream>>>(former, latter, gf, gl);
    fused_kernel<<<dim3(NBX, NBY, BB), 256, 0, stream>>>(gf, gl, flow1, flow2,
                                                         fw_mask, bw_mask, partials);
    reduce_kernel<<<1, 256, 0, stream>>>(partials, out);
}